// Round 4
// baseline (135.319 us; speedup 1.0000x reference)
//
#include <hip/hip_runtime.h>

// Problem constants (from reference)
#define DIM   128
#define KNEG  20

// Numerically stable log(sigmoid(x)) = -softplus(-x)
__device__ __forceinline__ float log_sigmoid(float x) {
    float ax = fabsf(x);
    float t = log1pf(__expf(-ax));
    return (x >= 0.0f) ? -t : (x - t);
}

// One batch element per 32-lane HALF-wave (2 elements per wave).
// A 128-float row = 512 B = 32 lanes x float4, so each half-wave covers a
// full row per load instruction.
//
// Round-4 change: MAXIMUM memory-level parallelism. All 22 row loads
// (U, positive, 20 negatives) are issued back-to-back into 22 independent
// float4 register destinations, then consumed in FIFO order (compiler can
// use incremental vmcnt waits). In-flight: 22 rows x 512 B x 2 halves =
// 22 KB/wave; ~350 KB/CU even at reduced occupancy — 16x the Little's-law
// requirement for 6.3 TB/s at ~900 ns HBM latency. Round-3's depth-8
// double-buffer got the kernel to ~26 us (inferred); compulsory-traffic
// floor is ~13.5 us (85 MB @ 6.3 TB/s). This is the decisive probe: if
// the total doesn't move, the kernel is overlapped with the unavoidable
// poison fills and the session is at the harness roofline.
__global__ __launch_bounds__(256) void skipgram_loss_kernel(
    const float* __restrict__ u_emb,   // [VOCAB, 128] float32
    const float* __restrict__ v_emb,   // [VOCAB, 128] float32
    const int* __restrict__ u_pos,     // [B] int32
    const int* __restrict__ v_pos,     // [B] int32
    const int* __restrict__ v_neg,     // [B, 20] int32
    float* __restrict__ partials,      // [gridDim.x] per-block partial sums
    int B_total)
{
    const int lane  = threadIdx.x & 63;
    const int wib   = threadIdx.x >> 6;         // wave in block (0..3)
    const int half  = lane >> 5;                // which half-wave (0/1)
    const int l32   = lane & 31;
    const int col   = l32 * 4;                  // float4 column within a row
    const int b     = (blockIdx.x * 4 + wib) * 2 + half;  // element for this half
    const int hbase = half << 5;

    float p = 0.0f, nd = 0.0f;
    const bool valid = (b < B_total);

    // Gather the 22 indices of this half's element with one load instruction:
    //   l32 0     -> v_pos[b]
    //   l32 1..20 -> v_neg[b*20 + l32-1]
    //   l32 21    -> u_pos[b]
    int myidx = 0;
    if (valid) {
        if (l32 == 0)            myidx = v_pos[b];
        else if (l32 <= KNEG)    myidx = v_neg[b * KNEG + l32 - 1];
        else if (l32 == 21)      myidx = u_pos[b];
    }

    if (valid) {
        const float* vcol = v_emb + col;

        // Issue ALL 22 independent row loads back-to-back.
        // L[0] = U row (oldest in FIFO, consumed first),
        // L[1] = positive v row, L[2..21] = negative v rows 1..20.
        float4 L[22];
        {
            const int ui = __shfl(myidx, hbase + 21, 64);
            L[0] = *(const float4*)(u_emb + (size_t)ui * DIM + col);
        }
        #pragma unroll
        for (int r = 0; r <= KNEG; ++r) {       // r=0: positive, r=1..20: negatives
            const int idx = __shfl(myidx, hbase + r, 64);
            L[r + 1] = *(const float4*)(vcol + (size_t)idx * DIM);
        }

        // Consume in load (FIFO) order.
        const float4 U = L[0];
        p = U.x * L[1].x + U.y * L[1].y + U.z * L[1].z + U.w * L[1].w;

        float4 ns = make_float4(0.f, 0.f, 0.f, 0.f);
        #pragma unroll
        for (int r = 2; r < 22; ++r) {
            ns.x += L[r].x; ns.y += L[r].y; ns.z += L[r].z; ns.w += L[r].w;
        }
        nd = U.x * ns.x + U.y * ns.y + U.z * ns.z + U.w * ns.w;
    }

    // Reduce within each 32-lane half (offsets < 32 stay inside the half)
    #pragma unroll
    for (int off = 16; off > 0; off >>= 1) {
        p  += __shfl_xor(p,  off, 64);
        nd += __shfl_xor(nd, off, 64);
    }

    float local = 0.0f;
    if (l32 == 0 && valid) {
        local = log_sigmoid(p) + log_sigmoid(-nd);
    }
    // Combine the two halves: lane0 += lane32's value
    local += __shfl_xor(local, 32, 64);

    // Block reduce (4 waves) -> plain store of this block's partial
    __shared__ float sbuf[4];
    if (lane == 0) sbuf[wib] = local;
    __syncthreads();
    if (threadIdx.x == 0) {
        partials[blockIdx.x] = sbuf[0] + sbuf[1] + sbuf[2] + sbuf[3];
    }
}

__global__ __launch_bounds__(256) void finalize_kernel(
    const float* __restrict__ partials, int n,
    const int* __restrict__ batch_size,
    float* __restrict__ out)
{
    const int lane = threadIdx.x & 63;
    const int wib  = threadIdx.x >> 6;

    float s = 0.0f;
    for (int i = threadIdx.x; i < n; i += 256) s += partials[i];

    #pragma unroll
    for (int off = 32; off > 0; off >>= 1) s += __shfl_xor(s, off, 64);

    __shared__ float sbuf[4];
    if (lane == 0) sbuf[wib] = s;
    __syncthreads();
    if (threadIdx.x == 0) {
        float total = sbuf[0] + sbuf[1] + sbuf[2] + sbuf[3];
        out[0] = -total / (float)batch_size[0];   // output is float32
    }
}

extern "C" void kernel_launch(void* const* d_in, const int* in_sizes, int n_in,
                              void* d_out, int out_size, void* d_ws, size_t ws_size,
                              hipStream_t stream) {
    const float* u_emb = (const float*)d_in[0];
    const float* v_emb = (const float*)d_in[1];
    const int* u_pos = (const int*)d_in[2];
    const int* v_pos = (const int*)d_in[3];
    const int* v_neg = (const int*)d_in[4];
    const int* bsz   = (const int*)d_in[5];

    const int B_total = in_sizes[2];           // 16384
    // 2 elements per wave, 4 waves per block -> 8 elements per block.
    const int blocks = (B_total + 7) / 8;      // 2048 blocks

    float* partials = (float*)d_ws;

    skipgram_loss_kernel<<<blocks, 256, 0, stream>>>(
        u_emb, v_emb, u_pos, v_pos, v_neg, partials, B_total);

    finalize_kernel<<<1, 256, 0, stream>>>(partials, blocks, bsz, (float*)d_out);
}